// Round 19
// baseline (66.111 us; speedup 1.0000x reference)
//
#include <hip/hip_runtime.h>
#include <hip/hip_bf16.h>

typedef __attribute__((ext_vector_type(8))) short short8;
typedef __attribute__((ext_vector_type(4))) short short4v;
typedef __attribute__((ext_vector_type(4))) float f32x4;

#define SCALE_QL 0.25504601521753316f   // (1/sqrt(32)) * log2(e)
#define LOG2E    1.4426950408889634f

__device__ __forceinline__ short f2bf(float f) {
  union { float f; unsigned u; } v; v.f = f;
  unsigned r = (v.u + 0x7fffu + ((v.u >> 16) & 1u)) >> 16;
  return (short)r;
}

union S8U { short8 v; __hip_bfloat162 h[4]; int2 d[2]; };
union W4U { int2 d; __hip_bfloat162 h[2]; };

__device__ __forceinline__ short8 pack8i(float4 a, float4 b) {
  S8U r;
  r.h[0] = __float22bfloat162_rn(make_float2(a.x, a.y));
  r.h[1] = __float22bfloat162_rn(make_float2(a.z, a.w));
  r.h[2] = __float22bfloat162_rn(make_float2(b.x, b.y));
  r.h[3] = __float22bfloat162_rn(make_float2(b.z, b.w));
  return r.v;
}

__device__ __forceinline__ short8 pack8f(f32x4 a, f32x4 b) {
  S8U r;
  r.h[0] = __float22bfloat162_rn(make_float2(a[0], a[1]));
  r.h[1] = __float22bfloat162_rn(make_float2(a[2], a[3]));
  r.h[2] = __float22bfloat162_rn(make_float2(b[0], b[1]));
  r.h[3] = __float22bfloat162_rn(make_float2(b[2], b[3]));
  return r.v;
}

__device__ __forceinline__ int2 pack4i(float a, float b, float c, float d) {
  W4U w;
  w.h[0] = __float22bfloat162_rn(make_float2(a, b));
  w.h[1] = __float22bfloat162_rn(make_float2(c, d));
  return w.d;
}

// ---------------------------------------------------------------------------
// k_prep: fragment-major pre-swizzle; bias table pre-multiplied by log2(e).
// ---------------------------------------------------------------------------
__global__ __launch_bounds__(256) void k_prep(
    const float* __restrict__ mask, const float* __restrict__ rpb,
    const float* __restrict__ qkvw, const float* __restrict__ pw,
    float* __restrict__ tabf, short* __restrict__ wfsw, short* __restrict__ pwsw)
{
  const int bid = blockIdx.x, tid = threadIdx.x;
  if (bid < 1024) {
    const int pair = bid >> 2;               // (wdx,h)
    const int wdx = pair >> 2, hh = pair & 3;
    int e = (bid & 3) * 256 + tid;           // [mt][nt][lane]
    int mt = e >> 8, nt = (e >> 6) & 3, ln = e & 63;
    int l = ln & 15, g = ln >> 4;
    int m = mt * 16 + l, n0 = nt * 16 + g * 4;
    float vv[4];
    #pragma unroll
    for (int j = 0; j < 4; ++j) {
      int n = n0 + j;
      float val;
      if (n >= 49)      val = -1e30f;
      else if (m >= 49) val = 0.0f;
      else {
        int mi = (m * 37) >> 8, mj = m - mi * 7;
        int ni = (n * 37) >> 8, nj = n - ni * 7;
        int ridx = (mi - ni + 6) * 13 + (mj - nj + 6);
        val = mask[(size_t)wdx * 2401 + m * 49 + n] + rpb[ridx * 4 + hh];
      }
      vv[j] = val * LOG2E;
    }
    float4* dst = reinterpret_cast<float4*>(&tabf[((size_t)pair * 1024 + e) * 4]);
    *dst = make_float4(vv[0], vv[1], vv[2], vv[3]);
  } else {
    int e = (bid - 1024) * 256 + tid;        // 0..8191
    const float* src;
    short* dst;
    if (e < 6144) {
      int hh = e / 1536, rem = e - hh * 1536;
      int slot = rem >> 8, ks = (rem >> 6) & 3, ln = rem & 63;
      int l = ln & 15, g = ln >> 4;
      int r = (slot >> 1) * 128 + hh * 32 + (slot & 1) * 16 + l;
      int c = ks * 32 + g * 8;
      src = &qkvw[(size_t)r * 128 + c];
      dst = wfsw + (size_t)e * 8;
    } else {
      int p = e - 6144;
      int nt = p >> 8, ks = (p >> 6) & 3, ln = p & 63;
      int l = ln & 15, g = ln >> 4;
      int r = nt * 16 + l, c = ks * 32 + g * 8;
      src = &pw[(size_t)r * 128 + c];
      dst = pwsw + (size_t)p * 8;
    }
    float4 a = *reinterpret_cast<const float4*>(src);
    float4 b = *reinterpret_cast<const float4*>(src + 4);
    *reinterpret_cast<short8*>(dst) = pack8i(a, b);
  }
}

// ---------------------------------------------------------------------------
// k_fused: OCCUPANCY PROBE — 512-thread blocks, 2 windows/block, 8 waves.
// Per-wave code identical to round 18 (wave = (window, head)); if the 12-
// wave/CU cap was block-count granularity, 2 blocks/CU now give 16 waves.
// ---------------------------------------------------------------------------
__global__ __launch_bounds__(512, 4) void k_fused(
    const float* __restrict__ x, const float* __restrict__ qkvb,
    const float* __restrict__ pb, const float* __restrict__ tabf,
    const short* __restrict__ wfsw, const short* __restrict__ pwsw,
    float* __restrict__ out)
{
  __shared__ short xs[2][64 * 136];    // x bf16 per window
  __shared__ short ao[2][64 * 136];    // attn-out bf16 per window
  const int tid = threadIdx.x;
  const int lane = tid & 63;
  const int h = (tid >> 6) & 3;
  const int win = tid >> 8;            // 0 or 1
  const int l15 = lane & 15, grp = lane >> 4;
  const int gwin = blockIdx.x * 2 + win;
  const int wdx = gwin & 63;
  const size_t xbase = (size_t)gwin * 49 * 128;
  const short* wfh = wfsw + (size_t)h * 6 * 4 * 64 * 8;
  const f32x4 zero4 = (f32x4){0, 0, 0, 0};
  short* const cs = xs[win];
  short* const co = ao[win];

  // ---- stage both windows' x (fp32 -> bf16, coalesced) + zero pads ----
  const size_t xb0 = (size_t)(blockIdx.x * 2) * 49 * 128;
  #pragma unroll
  for (int i = 0; i < 7; ++i) {
    int idx = tid + i * 512;
    if (idx < 3136) {
      int w = idx >= 1568;
      int rem = idx - (w ? 1568 : 0);
      int r = rem >> 5, c4 = rem & 31;
      float4 v = *reinterpret_cast<const float4*>(
          &x[xb0 + (size_t)w * 6272 + (size_t)r * 128 + c4 * 4]);
      *reinterpret_cast<int2*>(&xs[w][r * 136 + c4 * 4]) = pack4i(v.x, v.y, v.z, v.w);
    }
  }
  #pragma unroll
  for (int i = 0; i < 4; ++i) {
    int idx = tid + i * 512;
    if (idx < 1920) {
      int w = idx >= 960;
      int rem = idx - (w ? 960 : 0);
      int r = 49 + (rem >> 6), c = rem & 63;
      *reinterpret_cast<int*>(&xs[w][r * 136 + c * 2]) = 0;
    }
  }
  __syncthreads();   // B0: xs staged

  // ---- QK gemm (swapped), depth-2 wf pipeline ----
  f32x4 qk[4][4];
  #pragma unroll
  for (int nt = 0; nt < 4; ++nt) {
    int base = (nt < 2 ? 0 : 128) + h * 32 + (nt & 1) * 16 + grp * 4;
    float4 b4 = *reinterpret_cast<const float4*>(&qkvb[base]);
    #pragma unroll
    for (int tt = 0; tt < 4; ++tt) qk[tt][nt] = (f32x4){b4.x, b4.y, b4.z, b4.w};
  }
  {
    short8 wf2[2][4];
    #pragma unroll
    for (int p = 0; p < 2; ++p)
      #pragma unroll
      for (int nt = 0; nt < 4; ++nt)
        wf2[p][nt] = *reinterpret_cast<const short8*>(wfh + (((size_t)nt * 4 + p) * 64 + lane) * 8);
    __builtin_amdgcn_sched_barrier(0);
    #pragma unroll
    for (int ks = 0; ks < 4; ++ks) {
      const int b = ks & 1;
      __builtin_amdgcn_s_setprio(1);
      #pragma unroll
      for (int tt = 0; tt < 4; ++tt) {
        short8 xf = *reinterpret_cast<const short8*>(&cs[(tt * 16 + l15) * 136 + ks * 32 + grp * 8]);
        #pragma unroll
        for (int nt = 0; nt < 4; ++nt)
          qk[tt][nt] = __builtin_amdgcn_mfma_f32_16x16x32_bf16(wf2[b][nt], xf, qk[tt][nt], 0, 0, 0);
      }
      __builtin_amdgcn_s_setprio(0);
      if (ks < 2) {
        #pragma unroll
        for (int nt = 0; nt < 4; ++nt)
          wf2[b][nt] = *reinterpret_cast<const short8*>(wfh + (((size_t)nt * 4 + ks + 2) * 64 + lane) * 8);
        __builtin_amdgcn_sched_barrier(0);
      }
    }
  }
  short8 Qp[4], Kp[4];
  #pragma unroll
  for (int tt = 0; tt < 4; ++tt) {
    Qp[tt] = pack8f(qk[tt][0] * SCALE_QL, qk[tt][1] * SCALE_QL);  // log2e folded
    Kp[tt] = pack8f(qk[tt][2], qk[tt][3]);
  }

  // ---- V gemm (normal orientation), depth-2 wv pipeline ----
  short8 Vp[2][2];
  {
    f32x4 vacc[4][2];
    #pragma unroll
    for (int dt = 0; dt < 2; ++dt) {
      float bv = qkvb[256 + h * 32 + dt * 16 + l15];
      #pragma unroll
      for (int tt = 0; tt < 4; ++tt) vacc[tt][dt] = (f32x4){bv, bv, bv, bv};
    }
    short8 wv2[2][2];
    #pragma unroll
    for (int p = 0; p < 2; ++p)
      #pragma unroll
      for (int dt = 0; dt < 2; ++dt)
        wv2[p][dt] = *reinterpret_cast<const short8*>(wfh + ((((size_t)4 + dt) * 4 + p) * 64 + lane) * 8);
    __builtin_amdgcn_sched_barrier(0);
    #pragma unroll
    for (int ks = 0; ks < 4; ++ks) {
      const int b = ks & 1;
      __builtin_amdgcn_s_setprio(1);
      #pragma unroll
      for (int tt = 0; tt < 4; ++tt) {
        short8 xf = *reinterpret_cast<const short8*>(&cs[(tt * 16 + l15) * 136 + ks * 32 + grp * 8]);
        #pragma unroll
        for (int dt = 0; dt < 2; ++dt)
          vacc[tt][dt] = __builtin_amdgcn_mfma_f32_16x16x32_bf16(xf, wv2[b][dt], vacc[tt][dt], 0, 0, 0);
      }
      __builtin_amdgcn_s_setprio(0);
      if (ks < 2) {
        #pragma unroll
        for (int dt = 0; dt < 2; ++dt)
          wv2[b][dt] = *reinterpret_cast<const short8*>(wfh + ((((size_t)4 + dt) * 4 + ks + 2) * 64 + lane) * 8);
        __builtin_amdgcn_sched_barrier(0);
      }
    }
    #pragma unroll
    for (int k2 = 0; k2 < 2; ++k2)
      #pragma unroll
      for (int dt = 0; dt < 2; ++dt)
        Vp[k2][dt] = pack8f(vacc[2 * k2][dt], vacc[2 * k2 + 1][dt]);
  }

  // ---- bias-table prefetch for mt=0 (no barrier: ao separate buffer) ----
  const float* tbase = tabf + (((size_t)(wdx * 4 + h)) * 16) * 256;
  float4 tbc[4], tbn[4];
  #pragma unroll
  for (int nt = 0; nt < 4; ++nt)
    tbc[nt] = *reinterpret_cast<const float4*>(tbase + (((size_t)nt) * 64 + lane) * 4);

  // ---- ones fragment for the denominator MFMA ----
  const short ONEB = (short)0x3F80;    // bf16 1.0
  const short8 ones8 = (short8){ONEB, ONEB, ONEB, ONEB, ONEB, ONEB, ONEB, ONEB};

  // ---- per query-column-tile: S^T, exp2, PV + sum-MFMA -> ao buffer ----
  #pragma unroll
  for (int mt = 0; mt < 4; ++mt) {
    if (mt < 3) {
      #pragma unroll
      for (int nt = 0; nt < 4; ++nt)
        tbn[nt] = *reinterpret_cast<const float4*>(tbase + (((size_t)(mt + 1) * 4 + nt) * 64 + lane) * 4);
      __builtin_amdgcn_sched_barrier(0);
    }
    f32x4 s4[4];
    __builtin_amdgcn_s_setprio(1);
    #pragma unroll
    for (int nt = 0; nt < 4; ++nt)
      s4[nt] = __builtin_amdgcn_mfma_f32_16x16x32_bf16(Kp[nt], Qp[mt], zero4, 0, 0, 0);
    __builtin_amdgcn_s_setprio(0);
    const int m0 = mt * 16 + l15;
    #pragma unroll
    for (int nt = 0; nt < 4; ++nt) {
      s4[nt][0] = __builtin_amdgcn_exp2f(s4[nt][0] + tbc[nt].x);
      s4[nt][1] = __builtin_amdgcn_exp2f(s4[nt][1] + tbc[nt].y);
      s4[nt][2] = __builtin_amdgcn_exp2f(s4[nt][2] + tbc[nt].z);
      s4[nt][3] = __builtin_amdgcn_exp2f(s4[nt][3] + tbc[nt].w);
    }
    short8 Pp0 = pack8f(s4[0], s4[1]);   // unnormalized P (bf16)
    short8 Pp1 = pack8f(s4[2], s4[3]);
    __builtin_amdgcn_s_setprio(1);
    f32x4 sum4 = __builtin_amdgcn_mfma_f32_16x16x32_bf16(ones8, Pp0, zero4, 0, 0, 0);
    sum4 = __builtin_amdgcn_mfma_f32_16x16x32_bf16(ones8, Pp1, sum4, 0, 0, 0);
    __builtin_amdgcn_s_setprio(0);
    float ri = __builtin_amdgcn_rcpf(sum4[0]);
    #pragma unroll
    for (int dt = 0; dt < 2; ++dt) {
      __builtin_amdgcn_s_setprio(1);
      f32x4 ot = __builtin_amdgcn_mfma_f32_16x16x32_bf16(Vp[0][dt], Pp0, zero4, 0, 0, 0);
      ot = __builtin_amdgcn_mfma_f32_16x16x32_bf16(Vp[1][dt], Pp1, ot, 0, 0, 0);
      __builtin_amdgcn_s_setprio(0);
      *reinterpret_cast<int2*>(&co[m0 * 136 + h * 32 + dt * 16 + grp * 4]) =
          pack4i(ot[0] * ri, ot[1] * ri, ot[2] * ri, ot[3] * ri);
    }
    #pragma unroll
    for (int nt = 0; nt < 4; ++nt) tbc[nt] = tbn[nt];
  }

  // ---- preload proj B-frags for own 2 column-tiles + biases pre-B2 ----
  short8 pwf[2][4];
  #pragma unroll
  for (int n2 = 0; n2 < 2; ++n2)
    #pragma unroll
    for (int ks = 0; ks < 4; ++ks)
      pwf[n2][ks] = *reinterpret_cast<const short8*>(
          pwsw + (((size_t)(h * 2 + n2) * 4 + ks) * 64 + lane) * 8);
  float pbv[2];
  pbv[0] = pb[(h * 2) * 16 + l15];
  pbv[1] = pb[(h * 2 + 1) * 16 + l15];
  __syncthreads();   // B2: ao complete -> proj reads

  // ---- proj: own 2 output-column tiles x all 64 rows of own window ----
  #pragma unroll
  for (int tt = 0; tt < 4; ++tt) {
    short8 afr[4];
    #pragma unroll
    for (int ks = 0; ks < 4; ++ks)
      afr[ks] = *reinterpret_cast<const short8*>(&co[(tt * 16 + l15) * 136 + ks * 32 + grp * 8]);
    #pragma unroll
    for (int n2 = 0; n2 < 2; ++n2) {
      f32x4 pc = (f32x4){pbv[n2], pbv[n2], pbv[n2], pbv[n2]};
      __builtin_amdgcn_s_setprio(1);
      #pragma unroll
      for (int ks = 0; ks < 4; ++ks)
        pc = __builtin_amdgcn_mfma_f32_16x16x32_bf16(afr[ks], pwf[n2][ks], pc, 0, 0, 0);
      __builtin_amdgcn_s_setprio(0);
      #pragma unroll
      for (int r = 0; r < 4; ++r) {
        int m = tt * 16 + grp * 4 + r;
        if (m < 49)
          out[xbase + (size_t)m * 128 + (h * 2 + n2) * 16 + l15] = pc[r];
      }
    }
  }
}

// ---------------------------------------------------------------------------
extern "C" void kernel_launch(void* const* d_in, const int* in_sizes, int n_in,
                              void* d_out, int out_size, void* d_ws, size_t ws_size,
                              hipStream_t stream) {
  const float* x    = (const float*)d_in[0];
  const float* mask = (const float*)d_in[1];
  const float* qkvw = (const float*)d_in[2];
  const float* qkvb = (const float*)d_in[3];
  const float* rpb  = (const float*)d_in[4];
  const float* pw   = (const float*)d_in[5];
  const float* pb   = (const float*)d_in[6];
  float* out = (float*)d_out;

  char* ws = (char*)d_ws;
  short* wfsw = (short*)ws;                  // 4*6*4*64*16 B = 98,304 B
  short* pwsw = (short*)(ws + 98304);        // 8*4*64*16 B  = 32,768 B
  float* tabf = (float*)(ws + 131072);       // 256*16*64*16 B = 4,194,304 B

  k_prep <<<1056, 256, 0, stream>>>(mask, rpb, qkvw, pw, tabf, wfsw, pwsw);
  k_fused<<<2048, 512, 0, stream>>>(x, qkvb, pb, tabf, wfsw, pwsw, out);
}

// Round 20
// 61.003 us; speedup vs baseline: 1.0837x; 1.0837x over previous
//
#include <hip/hip_runtime.h>
#include <hip/hip_bf16.h>

typedef __attribute__((ext_vector_type(8))) short short8;
typedef __attribute__((ext_vector_type(4))) short short4v;
typedef __attribute__((ext_vector_type(4))) float f32x4;

#define SCALE_QL 0.25504601521753316f   // (1/sqrt(32)) * log2(e)
#define LOG2E    1.4426950408889634f

__device__ __forceinline__ short f2bf(float f) {
  union { float f; unsigned u; } v; v.f = f;
  unsigned r = (v.u + 0x7fffu + ((v.u >> 16) & 1u)) >> 16;
  return (short)r;
}

union S8U { short8 v; __hip_bfloat162 h[4]; int2 d[2]; };
union W4U { int2 d; __hip_bfloat162 h[2]; };

__device__ __forceinline__ short8 pack8i(float4 a, float4 b) {
  S8U r;
  r.h[0] = __float22bfloat162_rn(make_float2(a.x, a.y));
  r.h[1] = __float22bfloat162_rn(make_float2(a.z, a.w));
  r.h[2] = __float22bfloat162_rn(make_float2(b.x, b.y));
  r.h[3] = __float22bfloat162_rn(make_float2(b.z, b.w));
  return r.v;
}

__device__ __forceinline__ short8 pack8f(f32x4 a, f32x4 b) {
  S8U r;
  r.h[0] = __float22bfloat162_rn(make_float2(a[0], a[1]));
  r.h[1] = __float22bfloat162_rn(make_float2(a[2], a[3]));
  r.h[2] = __float22bfloat162_rn(make_float2(b[0], b[1]));
  r.h[3] = __float22bfloat162_rn(make_float2(b[2], b[3]));
  return r.v;
}

__device__ __forceinline__ int2 pack4i(float a, float b, float c, float d) {
  W4U w;
  w.h[0] = __float22bfloat162_rn(make_float2(a, b));
  w.h[1] = __float22bfloat162_rn(make_float2(c, d));
  return w.d;
}

// ---------------------------------------------------------------------------
// k_prep: fragment-major pre-swizzle. Bias table now BF16 (packed short8 x2
// per (mt,lane)): tabh[pair][mt][lane][16], values pre-multiplied by log2(e).
// Blocks 0..255: one block per (wdx,h) pair. Blocks 256..287: weights.
// ---------------------------------------------------------------------------
__global__ __launch_bounds__(256) void k_prep(
    const float* __restrict__ mask, const float* __restrict__ rpb,
    const float* __restrict__ qkvw, const float* __restrict__ pw,
    short* __restrict__ tabh, short* __restrict__ wfsw, short* __restrict__ pwsw)
{
  const int bid = blockIdx.x, tid = threadIdx.x;
  if (bid < 256) {
    const int wdx = bid >> 2, hh = bid & 3;
    const int mt = tid >> 6, ln = tid & 63;
    const int l = ln & 15, g = ln >> 4;
    const int m = mt * 16 + l;
    float vv[16];                            // [nt][r]
    #pragma unroll
    for (int nt = 0; nt < 4; ++nt) {
      #pragma unroll
      for (int r = 0; r < 4; ++r) {
        int n = nt * 16 + g * 4 + r;
        float val;
        if (n >= 49)      val = -1e30f;
        else if (m >= 49) val = 0.0f;
        else {
          int mi = (m * 37) >> 8, mj = m - mi * 7;
          int ni = (n * 37) >> 8, nj = n - ni * 7;
          int ridx = (mi - ni + 6) * 13 + (mj - nj + 6);
          val = mask[(size_t)wdx * 2401 + m * 49 + n] + rpb[ridx * 4 + hh];
        }
        vv[nt * 4 + r] = val * LOG2E;
      }
    }
    short* dst = tabh + (((size_t)bid * 4 + mt) * 64 + ln) * 16;
    short8 o0, o1;
    #pragma unroll
    for (int j = 0; j < 8; ++j) { o0[j] = f2bf(vv[j]); o1[j] = f2bf(vv[8 + j]); }
    *reinterpret_cast<short8*>(dst)     = o0;
    *reinterpret_cast<short8*>(dst + 8) = o1;
  } else {
    int e = (bid - 256) * 256 + tid;         // 0..8191
    const float* src;
    short* dst;
    if (e < 6144) {
      int hh = e / 1536, rem = e - hh * 1536;
      int slot = rem >> 8, ks = (rem >> 6) & 3, ln = rem & 63;
      int l = ln & 15, g = ln >> 4;
      int r = (slot >> 1) * 128 + hh * 32 + (slot & 1) * 16 + l;
      int c = ks * 32 + g * 8;
      src = &qkvw[(size_t)r * 128 + c];
      dst = wfsw + (size_t)e * 8;
    } else {
      int p = e - 6144;
      int nt = p >> 8, ks = (p >> 6) & 3, ln = p & 63;
      int l = ln & 15, g = ln >> 4;
      int r = nt * 16 + l, c = ks * 32 + g * 8;
      src = &pw[(size_t)r * 128 + c];
      dst = pwsw + (size_t)p * 8;
    }
    float4 a = *reinterpret_cast<const float4*>(src);
    float4 b = *reinterpret_cast<const float4*>(src + 4);
    *reinterpret_cast<short8*>(dst) = pack8i(a, b);
  }
}

// ---------------------------------------------------------------------------
// k_fused: round-18 structure (256 threads, wave=head, fused QK gemm,
// depth-2 pipelines, shuffle-free softmax, proj column-split, separate ao
// buffer, setprio). NEW: bf16 bias table — 2x16B loads per mt instead of
// 4, halves tab L2 traffic (262->131 MB kernel-wide), frees ~16 VGPRs.
// ---------------------------------------------------------------------------
__global__ __launch_bounds__(256, 4) void k_fused(
    const float* __restrict__ x, const float* __restrict__ qkvb,
    const float* __restrict__ pb, const short* __restrict__ tabh,
    const short* __restrict__ wfsw, const short* __restrict__ pwsw,
    float* __restrict__ out)
{
  __shared__ short xs[64 * 136];       // x bf16 [64][136]
  __shared__ short ao[64 * 136];       // attn-out bf16 [64][136]
  const int tid = threadIdx.x;
  const int lane = tid & 63;
  const int h = tid >> 6;
  const int l15 = lane & 15, grp = lane >> 4;
  // XCD-affinity swizzle: bijective on [0,4096); wdx mod 8 == blockIdx mod 8
  const int bswz = blockIdx.x;
  const int gwin = ((bswz >> 6) << 6) + (bswz & 7) + ((bswz >> 3) & 7) * 8;
  const int wdx = gwin & 63;
  const size_t xbase = (size_t)gwin * 49 * 128;
  const short* wfh = wfsw + (size_t)h * 6 * 4 * 64 * 8;
  const f32x4 zero4 = (f32x4){0, 0, 0, 0};

  // ---- stage x (fp32 -> bf16 via cvt_pk, coalesced) + zero pad rows ----
  #pragma unroll
  for (int i = 0; i < 7; ++i) {
    int idx = tid + i * 256;
    if (idx < 1568) {
      int r = idx >> 5, c4 = idx & 31;
      float4 v = *reinterpret_cast<const float4*>(&x[xbase + (size_t)r * 128 + c4 * 4]);
      *reinterpret_cast<int2*>(&xs[r * 136 + c4 * 4]) = pack4i(v.x, v.y, v.z, v.w);
    }
  }
  #pragma unroll
  for (int i = 0; i < 4; ++i) {
    int idx = tid + i * 256;
    if (idx < 960) {
      int r = 49 + (idx >> 6), c = idx & 63;
      *reinterpret_cast<int*>(&xs[r * 136 + c * 2]) = 0;
    }
  }
  __syncthreads();   // B0: xs staged

  // ---- QK gemm (swapped), depth-2 wf pipeline ----
  f32x4 qk[4][4];
  #pragma unroll
  for (int nt = 0; nt < 4; ++nt) {
    int base = (nt < 2 ? 0 : 128) + h * 32 + (nt & 1) * 16 + grp * 4;
    float4 b4 = *reinterpret_cast<const float4*>(&qkvb[base]);
    #pragma unroll
    for (int tt = 0; tt < 4; ++tt) qk[tt][nt] = (f32x4){b4.x, b4.y, b4.z, b4.w};
  }
  {
    short8 wf2[2][4];
    #pragma unroll
    for (int p = 0; p < 2; ++p)
      #pragma unroll
      for (int nt = 0; nt < 4; ++nt)
        wf2[p][nt] = *reinterpret_cast<const short8*>(wfh + (((size_t)nt * 4 + p) * 64 + lane) * 8);
    __builtin_amdgcn_sched_barrier(0);
    #pragma unroll
    for (int ks = 0; ks < 4; ++ks) {
      const int b = ks & 1;
      __builtin_amdgcn_s_setprio(1);
      #pragma unroll
      for (int tt = 0; tt < 4; ++tt) {
        short8 xf = *reinterpret_cast<const short8*>(&xs[(tt * 16 + l15) * 136 + ks * 32 + grp * 8]);
        #pragma unroll
        for (int nt = 0; nt < 4; ++nt)
          qk[tt][nt] = __builtin_amdgcn_mfma_f32_16x16x32_bf16(wf2[b][nt], xf, qk[tt][nt], 0, 0, 0);
      }
      __builtin_amdgcn_s_setprio(0);
      if (ks < 2) {
        #pragma unroll
        for (int nt = 0; nt < 4; ++nt)
          wf2[b][nt] = *reinterpret_cast<const short8*>(wfh + (((size_t)nt * 4 + ks + 2) * 64 + lane) * 8);
        __builtin_amdgcn_sched_barrier(0);
      }
    }
  }
  short8 Qp[4], Kp[4];
  #pragma unroll
  for (int tt = 0; tt < 4; ++tt) {
    Qp[tt] = pack8f(qk[tt][0] * SCALE_QL, qk[tt][1] * SCALE_QL);  // log2e folded
    Kp[tt] = pack8f(qk[tt][2], qk[tt][3]);
  }

  // ---- V gemm (normal orientation), depth-2 wv pipeline ----
  short8 Vp[2][2];
  {
    f32x4 vacc[4][2];
    #pragma unroll
    for (int dt = 0; dt < 2; ++dt) {
      float bv = qkvb[256 + h * 32 + dt * 16 + l15];
      #pragma unroll
      for (int tt = 0; tt < 4; ++tt) vacc[tt][dt] = (f32x4){bv, bv, bv, bv};
    }
    short8 wv2[2][2];
    #pragma unroll
    for (int p = 0; p < 2; ++p)
      #pragma unroll
      for (int dt = 0; dt < 2; ++dt)
        wv2[p][dt] = *reinterpret_cast<const short8*>(wfh + ((((size_t)4 + dt) * 4 + p) * 64 + lane) * 8);
    __builtin_amdgcn_sched_barrier(0);
    #pragma unroll
    for (int ks = 0; ks < 4; ++ks) {
      const int b = ks & 1;
      __builtin_amdgcn_s_setprio(1);
      #pragma unroll
      for (int tt = 0; tt < 4; ++tt) {
        short8 xf = *reinterpret_cast<const short8*>(&xs[(tt * 16 + l15) * 136 + ks * 32 + grp * 8]);
        #pragma unroll
        for (int dt = 0; dt < 2; ++dt)
          vacc[tt][dt] = __builtin_amdgcn_mfma_f32_16x16x32_bf16(xf, wv2[b][dt], vacc[tt][dt], 0, 0, 0);
      }
      __builtin_amdgcn_s_setprio(0);
      if (ks < 2) {
        #pragma unroll
        for (int dt = 0; dt < 2; ++dt)
          wv2[b][dt] = *reinterpret_cast<const short8*>(wfh + ((((size_t)4 + dt) * 4 + ks + 2) * 64 + lane) * 8);
        __builtin_amdgcn_sched_barrier(0);
      }
    }
    #pragma unroll
    for (int k2 = 0; k2 < 2; ++k2)
      #pragma unroll
      for (int dt = 0; dt < 2; ++dt)
        Vp[k2][dt] = pack8f(vacc[2 * k2][dt], vacc[2 * k2 + 1][dt]);
  }

  // ---- bias-table prefetch for mt=0 (bf16, 2 x 16B per mt) ----
  const short* tbase = tabh + (((size_t)(wdx * 4 + h)) * 4 * 64 + lane) * 16;
  short8 tbc[2], tbn[2];
  tbc[0] = *reinterpret_cast<const short8*>(tbase);
  tbc[1] = *reinterpret_cast<const short8*>(tbase + 8);

  // ---- ones fragment for the denominator MFMA ----
  const short ONEB = (short)0x3F80;    // bf16 1.0
  const short8 ones8 = (short8){ONEB, ONEB, ONEB, ONEB, ONEB, ONEB, ONEB, ONEB};

  // ---- per query-column-tile: S^T, exp2, PV + sum-MFMA -> ao buffer ----
  #pragma unroll
  for (int mt = 0; mt < 4; ++mt) {
    if (mt < 3) {
      tbn[0] = *reinterpret_cast<const short8*>(tbase + (mt + 1) * 64 * 16);
      tbn[1] = *reinterpret_cast<const short8*>(tbase + (mt + 1) * 64 * 16 + 8);
      __builtin_amdgcn_sched_barrier(0);
    }
    f32x4 s4[4];
    __builtin_amdgcn_s_setprio(1);
    #pragma unroll
    for (int nt = 0; nt < 4; ++nt)
      s4[nt] = __builtin_amdgcn_mfma_f32_16x16x32_bf16(Kp[nt], Qp[mt], zero4, 0, 0, 0);
    __builtin_amdgcn_s_setprio(0);
    const int m0 = mt * 16 + l15;
    // unpack bf16 bias and add; no max subtraction (bounded, exp2-safe)
    S8U t0, t1;
    t0.v = tbc[0]; t1.v = tbc[1];
    #pragma unroll
    for (int nt = 0; nt < 4; ++nt) {
      const S8U& tu = (nt < 2) ? t0 : t1;
      const int hb = (nt & 1) * 2;
      float2 a = make_float2(__bfloat162float(tu.h[hb].x), __bfloat162float(tu.h[hb].y));
      float2 b = make_float2(__bfloat162float(tu.h[hb + 1].x), __bfloat162float(tu.h[hb + 1].y));
      s4[nt][0] = __builtin_amdgcn_exp2f(s4[nt][0] + a.x);
      s4[nt][1] = __builtin_amdgcn_exp2f(s4[nt][1] + a.y);
      s4[nt][2] = __builtin_amdgcn_exp2f(s4[nt][2] + b.x);
      s4[nt][3] = __builtin_amdgcn_exp2f(s4[nt][3] + b.y);
    }
    short8 Pp0 = pack8f(s4[0], s4[1]);   // unnormalized P (bf16)
    short8 Pp1 = pack8f(s4[2], s4[3]);
    // denominator: every output row = sum_n P[n][m]; lane-local, no shuffles
    __builtin_amdgcn_s_setprio(1);
    f32x4 sum4 = __builtin_amdgcn_mfma_f32_16x16x32_bf16(ones8, Pp0, zero4, 0, 0, 0);
    sum4 = __builtin_amdgcn_mfma_f32_16x16x32_bf16(ones8, Pp1, sum4, 0, 0, 0);
    __builtin_amdgcn_s_setprio(0);
    float ri = __builtin_amdgcn_rcpf(sum4[0]);
    #pragma unroll
    for (int dt = 0; dt < 2; ++dt) {
      __builtin_amdgcn_s_setprio(1);
      f32x4 ot = __builtin_amdgcn_mfma_f32_16x16x32_bf16(Vp[0][dt], Pp0, zero4, 0, 0, 0);
      ot = __builtin_amdgcn_mfma_f32_16x16x32_bf16(Vp[1][dt], Pp1, ot, 0, 0, 0);
      __builtin_amdgcn_s_setprio(0);
      *reinterpret_cast<int2*>(&ao[m0 * 136 + h * 32 + dt * 16 + grp * 4]) =
          pack4i(ot[0] * ri, ot[1] * ri, ot[2] * ri, ot[3] * ri);
    }
    tbc[0] = tbn[0];
    tbc[1] = tbn[1];
  }

  // ---- preload ALL proj B-frags for own 2 column-tiles + biases pre-B2 ----
  short8 pwf[2][4];
  #pragma unroll
  for (int n2 = 0; n2 < 2; ++n2)
    #pragma unroll
    for (int ks = 0; ks < 4; ++ks)
      pwf[n2][ks] = *reinterpret_cast<const short8*>(
          pwsw + (((size_t)(h * 2 + n2) * 4 + ks) * 64 + lane) * 8);
  float pbv[2];
  pbv[0] = pb[(h * 2) * 16 + l15];
  pbv[1] = pb[(h * 2 + 1) * 16 + l15];
  __syncthreads();   // B2: ao complete -> proj reads

  // ---- proj: own 2 output-column tiles x all 64 rows; zero weight loads ----
  #pragma unroll
  for (int tt = 0; tt < 4; ++tt) {
    short8 afr[4];
    #pragma unroll
    for (int ks = 0; ks < 4; ++ks)
      afr[ks] = *reinterpret_cast<const short8*>(&ao[(tt * 16 + l15) * 136 + ks * 32 + grp * 8]);
    #pragma unroll
    for (int n2 = 0; n2 < 2; ++n2) {
      f32x4 pc = (f32x4){pbv[n2], pbv[n2], pbv[n2], pbv[n2]};
      __builtin_amdgcn_s_setprio(1);
      #pragma unroll
      for (int ks = 0; ks < 4; ++ks)
        pc = __builtin_amdgcn_mfma_f32_16x16x32_bf16(afr[ks], pwf[n2][ks], pc, 0, 0, 0);
      __builtin_amdgcn_s_setprio(0);
      #pragma unroll
      for (int r = 0; r < 4; ++r) {
        int m = tt * 16 + grp * 4 + r;
        if (m < 49)
          out[xbase + (size_t)m * 128 + (h * 2 + n2) * 16 + l15] = pc[r];
      }
    }
  }
}

// ---------------------------------------------------------------------------
extern "C" void kernel_launch(void* const* d_in, const int* in_sizes, int n_in,
                              void* d_out, int out_size, void* d_ws, size_t ws_size,
                              hipStream_t stream) {
  const float* x    = (const float*)d_in[0];
  const float* mask = (const float*)d_in[1];
  const float* qkvw = (const float*)d_in[2];
  const float* qkvb = (const float*)d_in[3];
  const float* rpb  = (const float*)d_in[4];
  const float* pw   = (const float*)d_in[5];
  const float* pb   = (const float*)d_in[6];
  float* out = (float*)d_out;

  char* ws = (char*)d_ws;
  short* wfsw = (short*)ws;                  // 4*6*4*64*16 B = 98,304 B
  short* pwsw = (short*)(ws + 98304);        // 8*4*64*16 B  = 32,768 B
  short* tabh = (short*)(ws + 131072);       // 256*4*64*32 B = 2,097,152 B

  k_prep <<<288,  256, 0, stream>>>(mask, rpb, qkvw, pw, tabh, wfsw, pwsw);
  k_fused<<<4096, 256, 0, stream>>>(x, qkvb, pb, tabh, wfsw, pwsw, out);
}